// Round 2
// baseline (37.791 us; speedup 1.0000x reference)
//
#include <hip/hip_runtime.h>

#define HEIGHT 8

// One block per box. Threads are i-major: lane -> (i = tid&7, j = tid>>3),
// so the valid (j < width) samples pack into the low waves with full 64-lane
// utilization during the gather, and fully-invalid waves fall through.
// Output order is restored via a 6 KB LDS tile + coalesced float4 stores.
__global__ void __launch_bounds__(512)
roi_rotate_kernel(const float* __restrict__ images,
                  const float* __restrict__ boxes,
                  const int* __restrict__ box_indices,
                  float* __restrict__ crops,
                  float* __restrict__ width_out,
                  int max_width, int Himg, int Wimg)
{
    const int m   = blockIdx.x;
    const int tid = threadIdx.x;
    const int mw  = max_width;

    // Per-box params are block-uniform -> scalar loads, no LDS/barrier needed.
    const float x1  = boxes[m * 5 + 0];
    const float y1  = boxes[m * 5 + 1];
    const float x2  = boxes[m * 5 + 2];
    const float y2  = boxes[m * 5 + 3];
    const float ang = boxes[m * 5 + 4];
    const float bwd = x2 - x1, bhd = y2 - y1;
    const float width = (float)HEIGHT * bwd / bhd;   // same assoc as reference
    const float cx = (x1 + x2) * 0.5f;
    const float cy = (y1 + y2) * 0.5f;
    const float s  = bhd / (float)HEIGHT;
    const float ca = cosf(ang);
    const float sa = sinf(ang);

    if (tid == 0) width_out[m] = (float)mw - width;

    const int i = tid & (HEIGHT - 1);   // i-major packing
    const int j = tid >> 3;

    const float dx = s * ((float)j - (width - 1.0f) * 0.5f);
    const float dy = s * ((float)i - ((float)HEIGHT - 1.0f) * 0.5f);
    const float sx = cx + ca * dx - sa * dy;
    const float sy = cy + sa * dx + ca * dy;

    float v0 = 0.0f, v1 = 0.0f, v2 = 0.0f;

    const bool valid = ((float)j < ceilf(width)) &&
                       (sx >= 0.0f) && (sx <= (float)(Wimg - 1)) &&
                       (sy >= 0.0f) && (sy <= (float)(Himg - 1));

    if (valid) {
        const float x0 = floorf(sx);
        const float y0 = floorf(sy);
        const float fx = sx - x0;
        const float fy = sy - y0;
        const int x0i = (int)fminf(fmaxf(x0,        0.0f), (float)(Wimg - 1));
        const int x1i = (int)fminf(fmaxf(x0 + 1.0f, 0.0f), (float)(Wimg - 1));
        const int y0i = (int)fminf(fmaxf(y0,        0.0f), (float)(Himg - 1));
        const int y1i = (int)fminf(fmaxf(y0 + 1.0f, 0.0f), (float)(Himg - 1));

        const int b = box_indices[m];
        const float* img = images + (size_t)b * Himg * Wimg * 3;
        const size_t o00 = ((size_t)y0i * Wimg + x0i) * 3;
        const size_t o01 = ((size_t)y0i * Wimg + x1i) * 3;
        const size_t o10 = ((size_t)y1i * Wimg + x0i) * 3;
        const size_t o11 = ((size_t)y1i * Wimg + x1i) * 3;

        const float w00 = (1.0f - fx) * (1.0f - fy);
        const float w01 = fx * (1.0f - fy);
        const float w10 = (1.0f - fx) * fy;
        const float w11 = fx * fy;

        v0 = img[o00 + 0] * w00 + img[o01 + 0] * w01 +
             img[o10 + 0] * w10 + img[o11 + 0] * w11;
        v1 = img[o00 + 1] * w00 + img[o01 + 1] * w01 +
             img[o10 + 1] * w10 + img[o11 + 1] * w11;
        v2 = img[o00 + 2] * w00 + img[o01 + 2] * w01 +
             img[o10 + 2] * w10 + img[o11 + 2] * w11;
    }

    // Stage in LDS (row-major output order, stride padded +4 floats ->
    // <=2-way bank aliasing on the 3-dword writes, free on CDNA4).
    __shared__ float lds[HEIGHT * (64 * 3 + 4)];
    const int STRIDE = 3 * mw + 4;
    float* dst = &lds[i * STRIDE + j * 3];
    dst[0] = v0; dst[1] = v1; dst[2] = v2;
    __syncthreads();

    // Coalesced vectorized store of the whole 8 x mw x 3 tile.
    float* oblk = crops + (size_t)m * HEIGHT * mw * 3;
    if ((mw & 3) == 0) {
        const int nf4 = (HEIGHT * mw * 3) >> 2;   // 6*mw <= blockDim
        if (tid < nf4) {
            const int f   = tid * 4;
            const int ii  = f / (3 * mw);
            const int rem = f - ii * (3 * mw);
            const float4 val = *(const float4*)&lds[ii * STRIDE + rem];
            *(float4*)&oblk[f] = val;
        }
    } else {
        float* o = oblk + ((size_t)i * mw + j) * 3;
        o[0] = v0; o[1] = v1; o[2] = v2;
    }
}

extern "C" void kernel_launch(void* const* d_in, const int* in_sizes, int n_in,
                              void* d_out, int out_size, void* d_ws, size_t ws_size,
                              hipStream_t stream) {
    const float* images      = (const float*)d_in[0];
    const float* boxes       = (const float*)d_in[2];
    const int*   box_indices = (const int*)d_in[3];

    const int M  = in_sizes[3];                       // 8192 boxes
    const int mw = (out_size - M) / (M * HEIGHT * 3); // max_width (=64)
    const int Himg = 512, Wimg = 512;

    float* crops     = (float*)d_out;
    float* width_out = crops + (size_t)M * HEIGHT * mw * 3;

    dim3 block(HEIGHT * mw);   // 512 threads = one box
    dim3 grid(M);
    roi_rotate_kernel<<<grid, block, 0, stream>>>(images, boxes, box_indices,
                                                  crops, width_out, mw, Himg, Wimg);
}